// Round 19
// baseline (1445.877 us; speedup 1.0000x reference)
//
#include <hip/hip_runtime.h>

#define TWO_PI 6.2831853071795864769f
#define SP3 327680      // 128*128*20
#define YT 2560         // 128*20

// cos/sin(2*pi*k/20) — compile-time twiddles; (kz*t)%20 indexes fold to literals.
static constexpr float TWC20[20]={
  1.0f, 0.9510565163f, 0.8090169944f, 0.5877852523f, 0.3090169944f,
  0.0f,-0.3090169944f,-0.5877852523f,-0.8090169944f,-0.9510565163f,
 -1.0f,-0.9510565163f,-0.8090169944f,-0.5877852523f,-0.3090169944f,
  0.0f, 0.3090169944f, 0.5877852523f, 0.8090169944f, 0.9510565163f};
static constexpr float TWS20[20]={
  0.0f, 0.3090169944f, 0.5877852523f, 0.8090169944f, 0.9510565163f,
  1.0f, 0.9510565163f, 0.8090169944f, 0.5877852523f, 0.3090169944f,
  0.0f,-0.3090169944f,-0.5877852523f,-0.8090169944f,-0.9510565163f,
 -1.0f,-0.9510565163f,-0.8090169944f,-0.5877852523f,-0.3090169944f};

// Branch-free gelu via A&S 7.1.26 erf approximation (|eps|<=1.5e-7).
static __device__ __forceinline__ float gelu_f(float u){
  float x=u*0.7071067811865475f;
  float a=fabsf(x);
  float t=__builtin_amdgcn_rcpf(fmaf(0.3275911f,a,1.0f));
  float p=fmaf(fmaf(fmaf(fmaf(1.061405429f,t,-1.453152027f),t,1.421413741f),t,
               -0.284496736f),t,0.254829592f)*t;
  float e=__expf(-a*a);
  float er=copysignf(1.0f-p*e,x);
  return 0.5f*u*(1.0f+er);
}

// ---------------- fc0 (unchanged)
__global__ void k_fc0(const float* __restrict__ x, const float* __restrict__ w,
                      const float* __restrict__ bias, float* __restrict__ h){
  __shared__ float wl[100], bl[20];
  int tid=threadIdx.x;
  if(tid<100) wl[tid]=w[tid];
  if(tid<20) bl[tid]=bias[tid];
  __syncthreads();
  int p=blockIdx.x*256+tid;
  int b=p/SP3, sp=p-b*SP3;
  const float* xp=x+(long)p*5;
  float xi[5];
  #pragma unroll
  for(int i=0;i<5;i++) xi[i]=xp[i];
  float* hb=h+(long)(b*32)*SP3+sp;
  #pragma unroll
  for(int c=0;c<20;c++){
    float a=bl[c];
    #pragma unroll
    for(int i=0;i<5;i++) a+=xi[i]*wl[i*20+c];
    hb[(long)c*SP3]=a;
  }
}

// ------------- forward T+Y DFT over 8-x slabs (unchanged from R15 — known good)
template<int M2>
__global__ __launch_bounds__(512,3) void k_fwd_ty8(const float* __restrict__ h,
                                                   float* __restrict__ Fty, int Ci){
  constexpr int J=2*M2*8;
  __shared__ float2 Gc[128*33];         // [y][col=xl*8+kz], pad 33
  __shared__ float2 tw128[128];
  int tid=threadIdx.x;
  int bid=blockIdx.x;
  int xg=bid&15, bc=bid>>4; int c=bc%Ci, b=bc/Ci;
  int x0=xg*8;
  if(tid<128){ float s,cc; sincosf(TWO_PI*tid/128.0f,&s,&cc); tw128[tid]=make_float2(cc,s); }
  __syncthreads();
  const float* hb=h+(long)(b*32+c)*SP3+x0*YT;
  float2* outp=(float2*)Fty+((long)(b*32+c)*128+x0)*J;

  for(int half=0;half<2;half++){
    if(half) __syncthreads();
    // ---- T-DFT: one row per thread, radix-2 over t, literal twiddles
    {
      int y=tid&127, xl=tid>>7;
      const float* rp=hb+(half*4+xl)*YT+y*20;
      float4 r0=*(const float4*)(rp);
      float4 r1=*(const float4*)(rp+4);
      float4 r2=*(const float4*)(rp+8);
      float4 r3=*(const float4*)(rp+12);
      float4 r4=*(const float4*)(rp+16);
      float row[20]={r0.x,r0.y,r0.z,r0.w, r1.x,r1.y,r1.z,r1.w, r2.x,r2.y,r2.z,r2.w,
                     r3.x,r3.y,r3.z,r3.w, r4.x,r4.y,r4.z,r4.w};
      float av[10],bv[10];
      #pragma unroll
      for(int t=0;t<10;t++){av[t]=row[t]+row[t+10]; bv[t]=row[t]-row[t+10];}
      float re[8],im[8];
      #pragma unroll
      for(int kz=0;kz<8;kz++){re[kz]=0.f;im[kz]=0.f;}
      #pragma unroll
      for(int t=0;t<10;t++){
        #pragma unroll
        for(int kz=0;kz<8;kz++){
          float v=(kz&1)?bv[t]:av[t];
          re[kz]+=v*TWC20[(kz*t)%20];
          im[kz]-=v*TWS20[(kz*t)%20];
        }
      }
      #pragma unroll
      for(int kz=0;kz<8;kz++) Gc[y*33+xl*8+kz]=make_float2(re[kz],im[kz]);
    }
    __syncthreads();
    // ---- radix-2 precombine: Gc[y] <- G[y]+G[y+64]; Gc[y+64] <- G[y]-G[y+64]
    for(int pi=tid;pi<2048;pi+=512){
      int y=pi>>5, col=pi&31;
      float2 a=Gc[y*33+col], bb=Gc[(y+64)*33+col];
      Gc[y*33+col]      =make_float2(a.x+bb.x, a.y+bb.y);
      Gc[(y+64)*33+col] =make_float2(a.x-bb.x, a.y-bb.y);
    }
    __syncthreads();
    // ---- Y-DFT: item=(sp,col), sp in [0,M2], 64-y loop, parity-selected half
    for(int ip=tid;ip<(M2+1)*32;ip+=512){
      int col=ip&31, sp=ip>>5;
      int off=(sp&1)?64:0;
      float a1r=0.f,a1i=0.f,a2r=0.f,a2i=0.f;
      int jj=0;
      for(int y=0;y<64;y++){
        float2 w=tw128[jj];
        float2 d=Gc[(y+off)*33+col];
        float tr=d.x*w.x, ts=d.y*w.y, ur=d.y*w.x, us=d.x*w.y;
        a1r+=tr+ts; a1i+=ur-us;          // slot sp      (km=+sp)
        a2r+=tr-ts; a2i+=ur+us;          // slot 2M2-sp  (km=-sp)
        jj=(jj+sp)&127;
      }
      int xl=col>>3, kz=col&7;
      long rowoff=(long)(half*4+xl)*J;
      if(sp<M2) outp[rowoff+sp*8+kz]=make_float2(a1r,a1i);
      if(sp>=1) outp[rowoff+(2*M2-sp)*8+kz]=make_float2(a2r,a2i);
    }
  }
}

// ------------- forward X DFT, slot-split (unchanged)
template<int M1,int M2>
__global__ __launch_bounds__(256,3) void k_fwd_x2(const float* __restrict__ Fty,
                                                  float* __restrict__ Fm, int Ci){
  constexpr int J=2*M2*8;
  constexpr int NIT=(M1*J+255)/256;
  __shared__ float2 tile[32*J];
  __shared__ float2 tw128[128];
  int tid=threadIdx.x, bid=blockIdx.x;
  int sh=bid&1; int c=(bid>>1)%Ci; int b=bid/(2*Ci);
  if(tid<128){ float s,cc; sincosf(TWO_PI*tid/128.0f,&s,&cc); tw128[tid]=make_float2(cc,s); }
  float accr[NIT],acci[NIT];
  #pragma unroll
  for(int it=0;it<NIT;it++){accr[it]=0.f;acci[it]=0.f;}
  const float2* base=(const float2*)Fty+((long)(b*32+c)*128)*J;
  for(int xt=0;xt<4;xt++){
    __syncthreads();
    const float2* src=base+(long)xt*32*J;
    for(int idx=tid;idx<32*J;idx+=256) tile[idx]=src[idx];
    __syncthreads();
    #pragma unroll
    for(int it=0;it<NIT;it++){
      int idx=it*256+tid;
      if(idx<M1*J){
        int si=idx/J, j=idx-si*J;
        int km=(sh==0)? si : (si-M1);
        int jj=(km*(xt*32))&127;
        float ar=accr[it], ai=acci[it];
        for(int xl=0;xl<32;xl++){
          float2 w=tw128[jj];
          float2 d=tile[xl*J+j];
          ar+=d.x*w.x+d.y*w.y;
          ai+=d.y*w.x-d.x*w.y;
          jj=(jj+km)&127;
        }
        accr[it]=ar; acci[it]=ai;
      }
    }
  }
  float2* o=(float2*)Fm+(long)(b*32+c)*(2*M1)*J;
  #pragma unroll
  for(int it=0;it<NIT;it++){
    int idx=it*256+tid;
    if(idx<M1*J){
      int si=idx/J, j=idx-si*J;
      int s=sh*M1+si;
      o[(long)s*J+j]=make_float2(accr[it],acci[it]);
    }
  }
}

// ------------- mode mixing (unchanged)
__global__ void k_mix(const float* __restrict__ Fm, const float* __restrict__ w,
                      float* __restrict__ Fm2, int Ci, int Co, int m1, int m2){
  int MC=m1*m2*8;
  int nch=MC/8;
  int bid=blockIdx.x;
  int chunk=bid%nch; int q=(bid/nch)&3; int b=bid/(4*nch);
  int tid=threadIdx.x;
  int M1S=2*m1, M2S=2*m2;
  int J=M2S*8;
  __shared__ float fin[32*16];
  for(int idx=tid;idx<Ci*16;idx+=blockDim.x){
    int i=idx>>4; int r=idx&15; int mll=r>>1; int ri=r&1;
    int mg=chunk*8+mll;
    int mx=mg/(m2*8); int my=(mg>>3)%m2; int kz=mg&7;
    int sx=(q&1)?(m1+mx):mx; int sy=(q&2)?(m2+my):my;
    fin[idx]=Fm[((long)((b*32+i)*M1S+sx)*J+sy*8+kz)*2+ri];
  }
  __syncthreads();
  int ml=tid&7, o=tid>>3;
  int mg=chunk*8+ml;
  int mx=mg/(m2*8); int my=(mg>>3)%m2; int kz=mg&7;
  int sx=(q&1)?(m1+mx):mx; int sy=(q&2)?(m2+my):my;
  int moff=(mx*m2+my)*8+kz;
  const float* wr=w+(long)(q*2)*Ci*Co*MC+o*MC+moff;
  const float* wi=wr+(long)Ci*Co*MC;
  long wstep=(long)Co*MC;
  float re=0.f, im=0.f;
  for(int i=0;i<Ci;i++){
    float ar=fin[i*16+ml*2], ai=fin[i*16+ml*2+1];
    float wrv=wr[i*wstep], wiv=wi[i*wstep];
    re+=ar*wrv-ai*wiv;
    im+=ar*wiv+ai*wrv;
  }
  long oidx=((long)((b*32+o)*M1S+sx)*J+sy*8+kz)*2;
  Fm2[oidx]=re; Fm2[oidx+1]=im;
}

// ------------- FUSED inverse X + Y + T, single-pass radix-2-over-y inverse-Y.
// LDS overlay: buf = [Fm2s | g1s]; So overlays from 0 AFTER g1s is dead (extra
// barrier). Total LDS 50.5KB (M=12) / 44KB (M=8) -> 3 blocks/CU.
template<int M>
__global__ __launch_bounds__(512,3) void k_inv_ytx8(const float* __restrict__ Fm2,
                                                    float* h, int Co, int do_gelu){
  constexpr int S1=2*M, S2=2*M;
  constexpr int J=S2*8;
  constexpr int FMS=S1*J*2;            // floats for Fm2s
  constexpr int G1F=S2*66*2;           // floats for g1s
  constexpr int UNF=(FMS+G1F>10752)?(FMS+G1F):10752;
  __shared__ __align__(16) float buf[UNF];     // Fm2s|g1s, later So
  __shared__ float2 tw128[128];
  int tid=threadIdx.x;
  int bid=blockIdx.x;
  int xg=bid&15, bo=bid>>4; int oc=bo%Co, b=bo/Co;
  int x0=xg*8;
  if(tid<128){ float s,cc; sincosf(TWO_PI*tid/128.0f,&s,&cc); tw128[tid]=make_float2(cc,s); }
  // ---- stage Fm2 tile (coalesced)
  float2* Fm2s=(float2*)buf;
  float2* g1s=(float2*)(buf+FMS);
  const float2* src=(const float2*)Fm2+(long)(b*32+oc)*S1*J;
  for(int idx=tid;idx<S1*J;idx+=512) Fm2s[idx]=src[idx];
  __syncthreads();
  // ---- inverse X: float2 reads, uniform tw128 broadcasts.
  for(int idx=tid;idx<8*J;idx+=512){
    int xl=idx/J, j=idx-xl*J;
    int xgl=x0+xl;
    float re=0.f, im=0.f;
    int jj=0;
    for(int s=0;s<M;s++){
      float2 w=tw128[jj]; float2 d=Fm2s[s*J+j];
      re+=d.x*w.x-d.y*w.y;
      im+=d.x*w.y+d.y*w.x;
      jj=(jj+xgl)&127;
    }
    jj=((128-M)*xgl)&127;
    for(int s=M;s<S1;s++){
      float2 w=tw128[jj]; float2 d=Fm2s[s*J+j];
      re+=d.x*w.x-d.y*w.y;
      im+=d.x*w.y+d.y*w.x;
      jj=(jj+xgl)&127;
    }
    g1s[(j>>3)*66 + xl*8 + (j&7)]=make_float2(re,im);
  }
  __syncthreads();                      // Fm2s dead (g1s live)
  float* So=buf;                        // overlays Fm2s+g1s — write only after
                                        // the post-accumulation barrier below
  const float invN=1.0f/(128.0f*128.0f*20.0f);
  float* hb=h+(long)(b*32+oc)*SP3+x0*YT;
  const float4* g4c=(const float4*)g1s;
  int y=tid&63, xl=tid>>6;              // xl wave-uniform (0..7)
  float Ser[8],Sei[8],Sor[8],Soi[8];
  // s=0 (km=0, w=1, even parity)
  {
    int base=(xl*8)>>1;
    #pragma unroll
    for(int q=0;q<4;q++){
      float4 d=g4c[base+q];
      Ser[2*q]=d.x;   Sei[2*q]=d.y;
      Ser[2*q+1]=d.z; Sei[2*q+1]=d.w;
      Sor[2*q]=0.f;   Soi[2*q]=0.f;
      Sor[2*q+1]=0.f; Soi[2*q+1]=0.f;
    }
  }
  // s=M (km=-M, M even -> even parity)
  {
    int jm=((128-M)*y)&127;
    float ang=(float)jm*(TWO_PI/128.0f);
    float wx=__cosf(ang), wy=__sinf(ang);
    int base=(M*66+xl*8)>>1;
    #pragma unroll
    for(int q=0;q<4;q++){
      float4 d=g4c[base+q];
      Ser[2*q]  +=d.x*wx-d.y*wy;  Sei[2*q]  +=d.x*wy+d.y*wx;
      Ser[2*q+1]+=d.z*wx-d.w*wy;  Sei[2*q+1]+=d.z*wy+d.w*wx;
    }
  }
  // conjugate pairs (s, S2-s), s=1..M-1: one sincos, parity-routed by s&1
  for(int s=1;s<M;s++){
    int jm=(s*y)&127;
    float ang=(float)jm*(TWO_PI/128.0f);
    float c=__cosf(ang), sn=__sinf(ang);
    int b1=(s*66+xl*8)>>1, b2=((S2-s)*66+xl*8)>>1;
    if(s&1){
      #pragma unroll
      for(int q=0;q<4;q++){
        float4 d1=g4c[b1+q], d2=g4c[b2+q];
        float Ax=d1.x+d2.x, By=d1.y-d2.y, Bx=d1.x-d2.x, Ay=d1.y+d2.y;
        Sor[2*q]  +=Ax*c-By*sn;  Soi[2*q]  +=Bx*sn+Ay*c;
        float Az=d1.z+d2.z, Bw=d1.w-d2.w, Bz=d1.z-d2.z, Aw=d1.w+d2.w;
        Sor[2*q+1]+=Az*c-Bw*sn;  Soi[2*q+1]+=Bz*sn+Aw*c;
      }
    }else{
      #pragma unroll
      for(int q=0;q<4;q++){
        float4 d1=g4c[b1+q], d2=g4c[b2+q];
        float Ax=d1.x+d2.x, By=d1.y-d2.y, Bx=d1.x-d2.x, Ay=d1.y+d2.y;
        Ser[2*q]  +=Ax*c-By*sn;  Sei[2*q]  +=Bx*sn+Ay*c;
        float Az=d1.z+d2.z, Bw=d1.w-d2.w, Bz=d1.z-d2.z, Aw=d1.w+d2.w;
        Ser[2*q+1]+=Az*c-Bw*sn;  Sei[2*q+1]+=Bz*sn+Aw*c;
      }
    }
  }
  __syncthreads();                      // all g1s reads done; So may now overlay
  // ---- combined inverse-T (linearity): row y -> So now; row y+64 -> o2 regs.
  float o2[20];
  int srow=xl*64+y;
  #pragma unroll
  for(int t=0;t<10;t++){
    float Ae=Ser[0], Be=Sor[0], Ao=0.f, Bo=0.f;
    #pragma unroll
    for(int kz=1;kz<8;kz++){
      float C2=2.0f*TWC20[(kz*t)%20], Sv=2.0f*TWS20[(kz*t)%20];
      if(kz&1){ Ao+=C2*Ser[kz]-Sv*Sei[kz]; Bo+=C2*Sor[kz]-Sv*Soi[kz]; }
      else    { Ae+=C2*Ser[kz]-Sv*Sei[kz]; Be+=C2*Sor[kz]-Sv*Soi[kz]; }
    }
    float E1=Ae+Be, O1=Ao+Bo, E2=Ae-Be, O2v=Ao-Bo;
    So[srow*21+t]   =(E1+O1)*invN;
    So[srow*21+t+10]=(E1-O1)*invN;
    o2[t]   =(E2+O2v)*invN;
    o2[t+10]=(E2-O2v)*invN;
  }
  __syncthreads();
  // ---- flush half 1: y<64 parts of all 8 rows (8 x 1280 contiguous floats)
  for(int f=tid;f<10240;f+=512){
    int xf=f/1280, rem=f-xf*1280;
    int rr=rem/20, t=rem-rr*20;
    float* dst=&hb[xf*YT+rem];
    float u=*dst+So[(xf*64+rr)*21+t];
    if(do_gelu) u=gelu_f(u);
    *dst=u;
  }
  __syncthreads();
  // ---- write row y+64 (held in regs), then flush half 2
  #pragma unroll
  for(int t=0;t<20;t++) So[srow*21+t]=o2[t];
  __syncthreads();
  for(int f=tid;f<10240;f+=512){
    int xf=f/1280, rem=f-xf*1280;
    int rr=rem/20, t=rem-rr*20;
    float* dst=&hb[xf*YT+1280+rem];
    float u=*dst+So[(xf*64+rr)*21+t];
    if(do_gelu) u=gelu_f(u);
    *dst=u;
  }
}

// ------------- pointwise conv IN-PLACE (unchanged)
template<int CO>
__global__ __launch_bounds__(256,4) void k_pconv2(float* h, const float* __restrict__ w,
                                                  const float* __restrict__ bias, int Ci){
  __shared__ __align__(16) float wt[32*CO];   // [i][o]
  __shared__ float bl[CO];
  int tid=threadIdx.x;
  for(int idx=tid;idx<Ci*CO;idx+=256){int i=idx/CO,o=idx-i*CO; wt[idx]=w[o*Ci+i];}
  if(tid<CO) bl[tid]=bias[tid];
  __syncthreads();
  long p=(long)blockIdx.x*512+tid*2;
  int b=(int)(p/SP3); int sp=(int)(p-(long)b*SP3);
  float* hb=h+(long)b*32*SP3+sp;
  float acc0[CO],acc1[CO];
  #pragma unroll
  for(int o=0;o<CO;o++){acc0[o]=bl[o];acc1[o]=bl[o];}
  for(int i=0;i<Ci;i++){
    float2 v=*(const float2*)&hb[(long)i*SP3];
    const float4* wc=(const float4*)&wt[i*CO];
    #pragma unroll
    for(int o4=0;o4<CO/4;o4++){
      float4 ww=wc[o4];
      acc0[4*o4+0]+=v.x*ww.x; acc0[4*o4+1]+=v.x*ww.y;
      acc0[4*o4+2]+=v.x*ww.z; acc0[4*o4+3]+=v.x*ww.w;
      acc1[4*o4+0]+=v.y*ww.x; acc1[4*o4+1]+=v.y*ww.y;
      acc1[4*o4+2]+=v.y*ww.z; acc1[4*o4+3]+=v.y*ww.w;
    }
  }
  #pragma unroll
  for(int o=0;o<CO;o++){
    *(float2*)&hb[(long)o*SP3]=make_float2(acc0[o],acc1[o]);
  }
}

// ------------- prep: transpose w1 (unchanged)
__global__ void k_prep_w1t(const float* __restrict__ w1, float* __restrict__ w1t){
  int idx=blockIdx.x*256+threadIdx.x;
  if(idx<4096){ int jj=idx>>5, i=idx&31; w1t[idx]=w1[i*128+jj]; }
}

// ------------- head, scalar-operand weights (unchanged)
__global__ __launch_bounds__(256,3) void k_head_s(const float* __restrict__ h,
                       const float* __restrict__ w1t, const float* __restrict__ b1,
                       const float* __restrict__ w2, const float* __restrict__ b2,
                       float* __restrict__ out){
  long p=(long)blockIdx.x*512+threadIdx.x;
  int b=(int)(p/SP3); int sp=(int)(p-(long)b*SP3);
  const float* hb=h+(long)b*32*SP3+sp;
  float hv0[32],hv1[32];
  #pragma unroll
  for(int i=0;i<32;i++){hv0[i]=hb[(long)i*SP3]; hv1[i]=hb[(long)i*SP3+256];}
  float a00=b2[0],a01=b2[1],a02=b2[2];
  float a10=a00,a11=a01,a12=a02;
  for(int jj=0;jj<128;jj++){
    const float* wc=w1t+jj*32;
    float u0=b1[jj], u1=u0;
    #pragma unroll
    for(int q=0;q<32;q++){
      float ww=wc[q];
      u0+=hv0[q]*ww;
      u1+=hv1[q]*ww;
    }
    u0=gelu_f(u0); u1=gelu_f(u1);
    float w20=w2[jj*3], w21=w2[jj*3+1], w22=w2[jj*3+2];
    a00+=u0*w20; a01+=u0*w21; a02+=u0*w22;
    a10+=u1*w20; a11+=u1*w21; a12+=u1*w22;
  }
  float* op=out+p*3;
  op[0]=a00; op[1]=a01; op[2]=a02;
  op=out+(p+256)*3;
  op[0]=a10; op[1]=a11; op[2]=a12;
}

// ------------- head fallback (LDS weights) for the low-workspace path
__global__ __launch_bounds__(256,4) void k_head2(const float* __restrict__ h,
                       const float* __restrict__ w1, const float* __restrict__ b1,
                       const float* __restrict__ w2, const float* __restrict__ b2,
                       float* __restrict__ out){
  __shared__ __align__(16) float w1t[128*32];
  __shared__ float b1l[128];
  __shared__ __align__(16) float4 w2l[128];
  __shared__ float b2l[3];
  int tid=threadIdx.x;
  for(int idx=tid;idx<4096;idx+=256){int jj=idx>>5,i=idx&31; w1t[idx]=w1[i*128+jj];}
  if(tid<128){b1l[tid]=b1[tid]; w2l[tid]=make_float4(w2[tid*3],w2[tid*3+1],w2[tid*3+2],0.f);}
  if(tid<3) b2l[tid]=b2[tid];
  __syncthreads();
  long p=(long)blockIdx.x*512+tid;
  int b=(int)(p/SP3); int sp=(int)(p-(long)b*SP3);
  const float* hb=h+(long)b*32*SP3+sp;
  float hv0[32],hv1[32];
  #pragma unroll
  for(int i=0;i<32;i++){hv0[i]=hb[(long)i*SP3]; hv1[i]=hb[(long)i*SP3+256];}
  float a00=b2l[0],a01=b2l[1],a02=b2l[2];
  float a10=a00,a11=a01,a12=a02;
  for(int jj=0;jj<128;jj++){
    const float4* wc=(const float4*)&w1t[jj*32];
    float u0=b1l[jj], u1=u0;
    #pragma unroll
    for(int q=0;q<8;q++){
      float4 ww=wc[q];
      u0+=hv0[4*q]*ww.x+hv0[4*q+1]*ww.y+hv0[4*q+2]*ww.z+hv0[4*q+3]*ww.w;
      u1+=hv1[4*q]*ww.x+hv1[4*q+1]*ww.y+hv1[4*q+2]*ww.z+hv1[4*q+3]*ww.w;
    }
    u0=gelu_f(u0); u1=gelu_f(u1);
    float4 w2v=w2l[jj];
    a00+=u0*w2v.x; a01+=u0*w2v.y; a02+=u0*w2v.z;
    a10+=u1*w2v.x; a11+=u1*w2v.y; a12+=u1*w2v.z;
  }
  float* op=out+p*3;
  op[0]=a00; op[1]=a01; op[2]=a02;
  op=out+(p+256)*3;
  op[0]=a10; op[1]=a11; op[2]=a12;
}

extern "C" void kernel_launch(void* const* d_in, const int* in_sizes, int n_in,
                              void* d_out, int out_size, void* d_ws, size_t ws_size,
                              hipStream_t stream){
  (void)in_sizes; (void)n_in; (void)out_size;
  const float* x    =(const float*)d_in[0];
  const float* fc0w =(const float*)d_in[1];
  const float* fc0b =(const float*)d_in[2];
  const float* sw[4]={(const float*)d_in[3],(const float*)d_in[6],(const float*)d_in[9],(const float*)d_in[12]};
  const float* cw[4]={(const float*)d_in[4],(const float*)d_in[7],(const float*)d_in[10],(const float*)d_in[13]};
  const float* cb[4]={(const float*)d_in[5],(const float*)d_in[8],(const float*)d_in[11],(const float*)d_in[14]};
  const float* fc1w =(const float*)d_in[15];
  const float* fc1b =(const float*)d_in[16];
  const float* fc2w =(const float*)d_in[17];
  const float* fc2b =(const float*)d_in[18];
  float* out=(float*)d_out;
  float* ws=(float*)d_ws;

  const long H_FLOATS   = 41943040L;
  const long FTY_FULL   = 6291456L;
  const long FM_FULL    = 1179648L;
  const long NEED_FULL  = H_FLOATS + FTY_FULL + 2*FM_FULL;

  float* h = ws;
  bool full = (ws_size >= (size_t)NEED_FULL*4);

  const int LAY[5]={20,24,24,32,32};
  const int M1A[4]={8,8,12,12};

  k_fc0<<<5120,256,0,stream>>>(x,fc0w,fc0b,h);

  for(int L=0;L<4;L++){
    int Ci=LAY[L], Co=LAY[L+1], m1=M1A[L], m2=M1A[L];
    int nch=m1*m2;
    long FM_B=(long)32*(2*m1)*(2*m2*8)*2;

    if(full){
      float* Fty=ws+H_FLOATS;
      float* Fm =ws+H_FLOATS+FTY_FULL;
      float* Fm2=ws+H_FLOATS+FTY_FULL+FM_FULL;
      if(m1==8)  k_fwd_ty8<8> <<<4*Ci*16,512,0,stream>>>(h,Fty,Ci);
      else       k_fwd_ty8<12><<<4*Ci*16,512,0,stream>>>(h,Fty,Ci);
      if(m1==8)  k_fwd_x2<8,8>  <<<4*Ci*2,256,0,stream>>>(Fty,Fm,Ci);
      else       k_fwd_x2<12,12><<<4*Ci*2,256,0,stream>>>(Fty,Fm,Ci);
      k_mix<<<4*4*nch,Co*8,0,stream>>>(Fm,sw[L],Fm2,Ci,Co,m1,m2);
      if(Co==24) k_pconv2<24><<<2560,256,0,stream>>>(h,cw[L],cb[L],Ci);
      else       k_pconv2<32><<<2560,256,0,stream>>>(h,cw[L],cb[L],Ci);
      if(m1==8)  k_inv_ytx8<8> <<<4*Co*16,512,0,stream>>>(Fm2,h,Co,(L!=3)?1:0);
      else       k_inv_ytx8<12><<<4*Co*16,512,0,stream>>>(Fm2,h,Co,(L!=3)?1:0);
    } else {
      float* Fty=out;
      float* Fm =out+1572864;
      float* Fm2=out+1867776;
      for(int b=0;b<4;b++){
        float* hbp=h+(long)b*32*SP3;
        if(m1==8)  k_fwd_ty8<8> <<<Ci*16,512,0,stream>>>(hbp,Fty,Ci);
        else       k_fwd_ty8<12><<<Ci*16,512,0,stream>>>(hbp,Fty,Ci);
        if(m1==8)  k_fwd_x2<8,8>  <<<Ci*2,256,0,stream>>>(Fty,Fm,Ci);
        else       k_fwd_x2<12,12><<<Ci*2,256,0,stream>>>(Fty,Fm,Ci);
        k_mix<<<4*nch,Co*8,0,stream>>>(Fm,sw[L],Fm2+b*FM_B,Ci,Co,m1,m2);
      }
      if(Co==24) k_pconv2<24><<<2560,256,0,stream>>>(h,cw[L],cb[L],Ci);
      else       k_pconv2<32><<<2560,256,0,stream>>>(h,cw[L],cb[L],Ci);
      for(int b=0;b<4;b++){
        float* hbp=h+(long)b*32*SP3;
        if(m1==8)  k_inv_ytx8<8> <<<Co*16,512,0,stream>>>(Fm2+b*FM_B,hbp,Co,(L!=3)?1:0);
        else       k_inv_ytx8<12><<<Co*16,512,0,stream>>>(Fm2+b*FM_B,hbp,Co,(L!=3)?1:0);
      }
    }
  }
  if(full){
    float* w1t=ws+H_FLOATS+FTY_FULL;
    k_prep_w1t<<<16,256,0,stream>>>(fc1w,w1t);
    k_head_s<<<2560,256,0,stream>>>(h,w1t,fc1b,fc2w,fc2b,out);
  } else {
    k_head2<<<2560,256,0,stream>>>(h,fc1w,fc1b,fc2w,fc2b,out);
  }
}

// Round 20
// 1429.603 us; speedup vs baseline: 1.0114x; 1.0114x over previous
//
#include <hip/hip_runtime.h>

#define TWO_PI 6.2831853071795864769f
#define SP3 327680      // 128*128*20
#define YT 2560         // 128*20

// cos/sin(2*pi*k/20) — compile-time twiddles; (kz*t)%20 indexes fold to literals.
static constexpr float TWC20[20]={
  1.0f, 0.9510565163f, 0.8090169944f, 0.5877852523f, 0.3090169944f,
  0.0f,-0.3090169944f,-0.5877852523f,-0.8090169944f,-0.9510565163f,
 -1.0f,-0.9510565163f,-0.8090169944f,-0.5877852523f,-0.3090169944f,
  0.0f, 0.3090169944f, 0.5877852523f, 0.8090169944f, 0.9510565163f};
static constexpr float TWS20[20]={
  0.0f, 0.3090169944f, 0.5877852523f, 0.8090169944f, 0.9510565163f,
  1.0f, 0.9510565163f, 0.8090169944f, 0.5877852523f, 0.3090169944f,
  0.0f,-0.3090169944f,-0.5877852523f,-0.8090169944f,-0.9510565163f,
 -1.0f,-0.9510565163f,-0.8090169944f,-0.5877852523f,-0.3090169944f};

// Branch-free gelu via A&S 7.1.26 erf approximation (|eps|<=1.5e-7).
static __device__ __forceinline__ float gelu_f(float u){
  float x=u*0.7071067811865475f;
  float a=fabsf(x);
  float t=__builtin_amdgcn_rcpf(fmaf(0.3275911f,a,1.0f));
  float p=fmaf(fmaf(fmaf(fmaf(1.061405429f,t,-1.453152027f),t,1.421413741f),t,
               -0.284496736f),t,0.254829592f)*t;
  float e=__expf(-a*a);
  float er=copysignf(1.0f-p*e,x);
  return 0.5f*u*(1.0f+er);
}

// ---------------- fc0 (unchanged)
__global__ void k_fc0(const float* __restrict__ x, const float* __restrict__ w,
                      const float* __restrict__ bias, float* __restrict__ h){
  __shared__ float wl[100], bl[20];
  int tid=threadIdx.x;
  if(tid<100) wl[tid]=w[tid];
  if(tid<20) bl[tid]=bias[tid];
  __syncthreads();
  int p=blockIdx.x*256+tid;
  int b=p/SP3, sp=p-b*SP3;
  const float* xp=x+(long)p*5;
  float xi[5];
  #pragma unroll
  for(int i=0;i<5;i++) xi[i]=xp[i];
  float* hb=h+(long)(b*32)*SP3+sp;
  #pragma unroll
  for(int c=0;c<20;c++){
    float a=bl[c];
    #pragma unroll
    for(int i=0;i<5;i++) a+=xi[i]*wl[i*20+c];
    hb[(long)c*SP3]=a;
  }
}

// ------------- forward T+Y DFT over 8-x slabs (unchanged — known good)
template<int M2>
__global__ __launch_bounds__(512,3) void k_fwd_ty8(const float* __restrict__ h,
                                                   float* __restrict__ Fty, int Ci){
  constexpr int J=2*M2*8;
  __shared__ float2 Gc[128*33];         // [y][col=xl*8+kz], pad 33
  __shared__ float2 tw128[128];
  int tid=threadIdx.x;
  int bid=blockIdx.x;
  int xg=bid&15, bc=bid>>4; int c=bc%Ci, b=bc/Ci;
  int x0=xg*8;
  if(tid<128){ float s,cc; sincosf(TWO_PI*tid/128.0f,&s,&cc); tw128[tid]=make_float2(cc,s); }
  __syncthreads();
  const float* hb=h+(long)(b*32+c)*SP3+x0*YT;
  float2* outp=(float2*)Fty+((long)(b*32+c)*128+x0)*J;

  for(int half=0;half<2;half++){
    if(half) __syncthreads();
    // ---- T-DFT: one row per thread, radix-2 over t, literal twiddles
    {
      int y=tid&127, xl=tid>>7;
      const float* rp=hb+(half*4+xl)*YT+y*20;
      float4 r0=*(const float4*)(rp);
      float4 r1=*(const float4*)(rp+4);
      float4 r2=*(const float4*)(rp+8);
      float4 r3=*(const float4*)(rp+12);
      float4 r4=*(const float4*)(rp+16);
      float row[20]={r0.x,r0.y,r0.z,r0.w, r1.x,r1.y,r1.z,r1.w, r2.x,r2.y,r2.z,r2.w,
                     r3.x,r3.y,r3.z,r3.w, r4.x,r4.y,r4.z,r4.w};
      float av[10],bv[10];
      #pragma unroll
      for(int t=0;t<10;t++){av[t]=row[t]+row[t+10]; bv[t]=row[t]-row[t+10];}
      float re[8],im[8];
      #pragma unroll
      for(int kz=0;kz<8;kz++){re[kz]=0.f;im[kz]=0.f;}
      #pragma unroll
      for(int t=0;t<10;t++){
        #pragma unroll
        for(int kz=0;kz<8;kz++){
          float v=(kz&1)?bv[t]:av[t];
          re[kz]+=v*TWC20[(kz*t)%20];
          im[kz]-=v*TWS20[(kz*t)%20];
        }
      }
      #pragma unroll
      for(int kz=0;kz<8;kz++) Gc[y*33+xl*8+kz]=make_float2(re[kz],im[kz]);
    }
    __syncthreads();
    // ---- radix-2 precombine: Gc[y] <- G[y]+G[y+64]; Gc[y+64] <- G[y]-G[y+64]
    for(int pi=tid;pi<2048;pi+=512){
      int y=pi>>5, col=pi&31;
      float2 a=Gc[y*33+col], bb=Gc[(y+64)*33+col];
      Gc[y*33+col]      =make_float2(a.x+bb.x, a.y+bb.y);
      Gc[(y+64)*33+col] =make_float2(a.x-bb.x, a.y-bb.y);
    }
    __syncthreads();
    // ---- Y-DFT: item=(sp,col), sp in [0,M2], 64-y loop, parity-selected half
    for(int ip=tid;ip<(M2+1)*32;ip+=512){
      int col=ip&31, sp=ip>>5;
      int off=(sp&1)?64:0;
      float a1r=0.f,a1i=0.f,a2r=0.f,a2i=0.f;
      int jj=0;
      for(int y=0;y<64;y++){
        float2 w=tw128[jj];
        float2 d=Gc[(y+off)*33+col];
        float tr=d.x*w.x, ts=d.y*w.y, ur=d.y*w.x, us=d.x*w.y;
        a1r+=tr+ts; a1i+=ur-us;          // slot sp      (km=+sp)
        a2r+=tr-ts; a2i+=ur+us;          // slot 2M2-sp  (km=-sp)
        jj=(jj+sp)&127;
      }
      int xl=col>>3, kz=col&7;
      long rowoff=(long)(half*4+xl)*J;
      if(sp<M2) outp[rowoff+sp*8+kz]=make_float2(a1r,a1i);
      if(sp>=1) outp[rowoff+(2*M2-sp)*8+kz]=make_float2(a2r,a2i);
    }
  }
}

// ------------- forward X DFT, slot-split (unchanged)
template<int M1,int M2>
__global__ __launch_bounds__(256,3) void k_fwd_x2(const float* __restrict__ Fty,
                                                  float* __restrict__ Fm, int Ci){
  constexpr int J=2*M2*8;
  constexpr int NIT=(M1*J+255)/256;
  __shared__ float2 tile[32*J];
  __shared__ float2 tw128[128];
  int tid=threadIdx.x, bid=blockIdx.x;
  int sh=bid&1; int c=(bid>>1)%Ci; int b=bid/(2*Ci);
  if(tid<128){ float s,cc; sincosf(TWO_PI*tid/128.0f,&s,&cc); tw128[tid]=make_float2(cc,s); }
  float accr[NIT],acci[NIT];
  #pragma unroll
  for(int it=0;it<NIT;it++){accr[it]=0.f;acci[it]=0.f;}
  const float2* base=(const float2*)Fty+((long)(b*32+c)*128)*J;
  for(int xt=0;xt<4;xt++){
    __syncthreads();
    const float2* src=base+(long)xt*32*J;
    for(int idx=tid;idx<32*J;idx+=256) tile[idx]=src[idx];
    __syncthreads();
    #pragma unroll
    for(int it=0;it<NIT;it++){
      int idx=it*256+tid;
      if(idx<M1*J){
        int si=idx/J, j=idx-si*J;
        int km=(sh==0)? si : (si-M1);
        int jj=(km*(xt*32))&127;
        float ar=accr[it], ai=acci[it];
        for(int xl=0;xl<32;xl++){
          float2 w=tw128[jj];
          float2 d=tile[xl*J+j];
          ar+=d.x*w.x+d.y*w.y;
          ai+=d.y*w.x-d.x*w.y;
          jj=(jj+km)&127;
        }
        accr[it]=ar; acci[it]=ai;
      }
    }
  }
  float2* o=(float2*)Fm+(long)(b*32+c)*(2*M1)*J;
  #pragma unroll
  for(int it=0;it<NIT;it++){
    int idx=it*256+tid;
    if(idx<M1*J){
      int si=idx/J, j=idx-si*J;
      int s=sh*M1+si;
      o[(long)s*J+j]=make_float2(accr[it],acci[it]);
    }
  }
}

// ------------- mode mixing (unchanged)
__global__ void k_mix(const float* __restrict__ Fm, const float* __restrict__ w,
                      float* __restrict__ Fm2, int Ci, int Co, int m1, int m2){
  int MC=m1*m2*8;
  int nch=MC/8;
  int bid=blockIdx.x;
  int chunk=bid%nch; int q=(bid/nch)&3; int b=bid/(4*nch);
  int tid=threadIdx.x;
  int M1S=2*m1, M2S=2*m2;
  int J=M2S*8;
  __shared__ float fin[32*16];
  for(int idx=tid;idx<Ci*16;idx+=blockDim.x){
    int i=idx>>4; int r=idx&15; int mll=r>>1; int ri=r&1;
    int mg=chunk*8+mll;
    int mx=mg/(m2*8); int my=(mg>>3)%m2; int kz=mg&7;
    int sx=(q&1)?(m1+mx):mx; int sy=(q&2)?(m2+my):my;
    fin[idx]=Fm[((long)((b*32+i)*M1S+sx)*J+sy*8+kz)*2+ri];
  }
  __syncthreads();
  int ml=tid&7, o=tid>>3;
  int mg=chunk*8+ml;
  int mx=mg/(m2*8); int my=(mg>>3)%m2; int kz=mg&7;
  int sx=(q&1)?(m1+mx):mx; int sy=(q&2)?(m2+my):my;
  int moff=(mx*m2+my)*8+kz;
  const float* wr=w+(long)(q*2)*Ci*Co*MC+o*MC+moff;
  const float* wi=wr+(long)Ci*Co*MC;
  long wstep=(long)Co*MC;
  float re=0.f, im=0.f;
  for(int i=0;i<Ci;i++){
    float ar=fin[i*16+ml*2], ai=fin[i*16+ml*2+1];
    float wrv=wr[i*wstep], wiv=wi[i*wstep];
    re+=ar*wrv-ai*wiv;
    im+=ar*wiv+ai*wrv;
  }
  long oidx=((long)((b*32+o)*M1S+sx)*J+sy*8+kz)*2;
  Fm2[oidx]=re; Fm2[oidx+1]=im;
}

// ------------- FUSED inverse X + Y + T, single-pass radix-2-over-y inverse-Y.
// VGPR diet: no o2[] — row y+64's inverse-T is RECOMPUTED from the still-live
// Se/So parity sums after flush 1 (saves 20 held regs; costs ~280 ops).
template<int M>
__global__ __launch_bounds__(512,3) void k_inv_ytx8(const float* __restrict__ Fm2,
                                                    float* h, int Co, int do_gelu){
  constexpr int S1=2*M, S2=2*M;
  constexpr int J=S2*8;
  constexpr int FMS=S1*J*2;            // floats for Fm2s
  constexpr int G1F=S2*66*2;           // floats for g1s
  constexpr int UNF=(FMS+G1F>10752)?(FMS+G1F):10752;
  __shared__ __align__(16) float buf[UNF];     // Fm2s|g1s, later So
  __shared__ float2 tw128[128];
  int tid=threadIdx.x;
  int bid=blockIdx.x;
  int xg=bid&15, bo=bid>>4; int oc=bo%Co, b=bo/Co;
  int x0=xg*8;
  if(tid<128){ float s,cc; sincosf(TWO_PI*tid/128.0f,&s,&cc); tw128[tid]=make_float2(cc,s); }
  // ---- stage Fm2 tile (coalesced)
  float2* Fm2s=(float2*)buf;
  float2* g1s=(float2*)(buf+FMS);
  const float2* src=(const float2*)Fm2+(long)(b*32+oc)*S1*J;
  for(int idx=tid;idx<S1*J;idx+=512) Fm2s[idx]=src[idx];
  __syncthreads();
  // ---- inverse X: float2 reads, uniform tw128 broadcasts.
  for(int idx=tid;idx<8*J;idx+=512){
    int xl=idx/J, j=idx-xl*J;
    int xgl=x0+xl;
    float re=0.f, im=0.f;
    int jj=0;
    for(int s=0;s<M;s++){
      float2 w=tw128[jj]; float2 d=Fm2s[s*J+j];
      re+=d.x*w.x-d.y*w.y;
      im+=d.x*w.y+d.y*w.x;
      jj=(jj+xgl)&127;
    }
    jj=((128-M)*xgl)&127;
    for(int s=M;s<S1;s++){
      float2 w=tw128[jj]; float2 d=Fm2s[s*J+j];
      re+=d.x*w.x-d.y*w.y;
      im+=d.x*w.y+d.y*w.x;
      jj=(jj+xgl)&127;
    }
    g1s[(j>>3)*66 + xl*8 + (j&7)]=make_float2(re,im);
  }
  __syncthreads();                      // Fm2s dead (g1s live)
  float* So=buf;                        // overlays Fm2s+g1s — write only after
                                        // the post-accumulation barrier below
  const float invN=1.0f/(128.0f*128.0f*20.0f);
  float* hb=h+(long)(b*32+oc)*SP3+x0*YT;
  const float4* g4c=(const float4*)g1s;
  int y=tid&63, xl=tid>>6;              // xl wave-uniform (0..7)
  float Ser[8],Sei[8],Sor[8],Soi[8];
  // s=0 (km=0, w=1, even parity)
  {
    int base=(xl*8)>>1;
    #pragma unroll
    for(int q=0;q<4;q++){
      float4 d=g4c[base+q];
      Ser[2*q]=d.x;   Sei[2*q]=d.y;
      Ser[2*q+1]=d.z; Sei[2*q+1]=d.w;
      Sor[2*q]=0.f;   Soi[2*q]=0.f;
      Sor[2*q+1]=0.f; Soi[2*q+1]=0.f;
    }
  }
  // s=M (km=-M, M even -> even parity)
  {
    int jm=((128-M)*y)&127;
    float ang=(float)jm*(TWO_PI/128.0f);
    float wx=__cosf(ang), wy=__sinf(ang);
    int base=(M*66+xl*8)>>1;
    #pragma unroll
    for(int q=0;q<4;q++){
      float4 d=g4c[base+q];
      Ser[2*q]  +=d.x*wx-d.y*wy;  Sei[2*q]  +=d.x*wy+d.y*wx;
      Ser[2*q+1]+=d.z*wx-d.w*wy;  Sei[2*q+1]+=d.z*wy+d.w*wx;
    }
  }
  // conjugate pairs (s, S2-s), s=1..M-1: one sincos, parity-routed by s&1
  for(int s=1;s<M;s++){
    int jm=(s*y)&127;
    float ang=(float)jm*(TWO_PI/128.0f);
    float c=__cosf(ang), sn=__sinf(ang);
    int b1=(s*66+xl*8)>>1, b2=((S2-s)*66+xl*8)>>1;
    if(s&1){
      #pragma unroll
      for(int q=0;q<4;q++){
        float4 d1=g4c[b1+q], d2=g4c[b2+q];
        float Ax=d1.x+d2.x, By=d1.y-d2.y, Bx=d1.x-d2.x, Ay=d1.y+d2.y;
        Sor[2*q]  +=Ax*c-By*sn;  Soi[2*q]  +=Bx*sn+Ay*c;
        float Az=d1.z+d2.z, Bw=d1.w-d2.w, Bz=d1.z-d2.z, Aw=d1.w+d2.w;
        Sor[2*q+1]+=Az*c-Bw*sn;  Soi[2*q+1]+=Bz*sn+Aw*c;
      }
    }else{
      #pragma unroll
      for(int q=0;q<4;q++){
        float4 d1=g4c[b1+q], d2=g4c[b2+q];
        float Ax=d1.x+d2.x, By=d1.y-d2.y, Bx=d1.x-d2.x, Ay=d1.y+d2.y;
        Ser[2*q]  +=Ax*c-By*sn;  Sei[2*q]  +=Bx*sn+Ay*c;
        float Az=d1.z+d2.z, Bw=d1.w-d2.w, Bz=d1.z-d2.z, Aw=d1.w+d2.w;
        Ser[2*q+1]+=Az*c-Bw*sn;  Sei[2*q+1]+=Bz*sn+Aw*c;
      }
    }
  }
  __syncthreads();                      // all g1s reads done; So may now overlay
  int srow=xl*64+y;
  // ---- inverse-T for row y (E1 = Ae+Be, O1 = Ao+Bo); write So.
  #pragma unroll
  for(int t=0;t<10;t++){
    float Ae=Ser[0], Be=Sor[0], Ao=0.f, Bo=0.f;
    #pragma unroll
    for(int kz=1;kz<8;kz++){
      float C2=2.0f*TWC20[(kz*t)%20], Sv=2.0f*TWS20[(kz*t)%20];
      if(kz&1){ Ao+=C2*Ser[kz]-Sv*Sei[kz]; Bo+=C2*Sor[kz]-Sv*Soi[kz]; }
      else    { Ae+=C2*Ser[kz]-Sv*Sei[kz]; Be+=C2*Sor[kz]-Sv*Soi[kz]; }
    }
    float E1=Ae+Be, O1=Ao+Bo;
    So[srow*21+t]   =(E1+O1)*invN;
    So[srow*21+t+10]=(E1-O1)*invN;
  }
  __syncthreads();
  // ---- flush half 1: y<64 parts of all 8 rows (8 x 1280 contiguous floats)
  for(int f=tid;f<10240;f+=512){
    int xf=f/1280, rem=f-xf*1280;
    int rr=rem/20, t=rem-rr*20;
    float* dst=&hb[xf*YT+rem];
    float u=*dst+So[(xf*64+rr)*21+t];
    if(do_gelu) u=gelu_f(u);
    *dst=u;
  }
  __syncthreads();
  // ---- inverse-T for row y+64 (E2 = Ae-Be, O2 = Ao-Bo), recomputed; write So.
  #pragma unroll
  for(int t=0;t<10;t++){
    float Ae=Ser[0], Be=Sor[0], Ao=0.f, Bo=0.f;
    #pragma unroll
    for(int kz=1;kz<8;kz++){
      float C2=2.0f*TWC20[(kz*t)%20], Sv=2.0f*TWS20[(kz*t)%20];
      if(kz&1){ Ao+=C2*Ser[kz]-Sv*Sei[kz]; Bo+=C2*Sor[kz]-Sv*Soi[kz]; }
      else    { Ae+=C2*Ser[kz]-Sv*Sei[kz]; Be+=C2*Sor[kz]-Sv*Soi[kz]; }
    }
    float E2=Ae-Be, O2v=Ao-Bo;
    So[srow*21+t]   =(E2+O2v)*invN;
    So[srow*21+t+10]=(E2-O2v)*invN;
  }
  __syncthreads();
  // ---- flush half 2: y>=64 parts (contiguous, offset 1280 within each row)
  for(int f=tid;f<10240;f+=512){
    int xf=f/1280, rem=f-xf*1280;
    int rr=rem/20, t=rem-rr*20;
    float* dst=&hb[xf*YT+1280+rem];
    float u=*dst+So[(xf*64+rr)*21+t];
    if(do_gelu) u=gelu_f(u);
    *dst=u;
  }
}

// ------------- pointwise conv IN-PLACE (unchanged)
template<int CO>
__global__ __launch_bounds__(256,4) void k_pconv2(float* h, const float* __restrict__ w,
                                                  const float* __restrict__ bias, int Ci){
  __shared__ __align__(16) float wt[32*CO];   // [i][o]
  __shared__ float bl[CO];
  int tid=threadIdx.x;
  for(int idx=tid;idx<Ci*CO;idx+=256){int i=idx/CO,o=idx-i*CO; wt[idx]=w[o*Ci+i];}
  if(tid<CO) bl[tid]=bias[tid];
  __syncthreads();
  long p=(long)blockIdx.x*512+tid*2;
  int b=(int)(p/SP3); int sp=(int)(p-(long)b*SP3);
  float* hb=h+(long)b*32*SP3+sp;
  float acc0[CO],acc1[CO];
  #pragma unroll
  for(int o=0;o<CO;o++){acc0[o]=bl[o];acc1[o]=bl[o];}
  for(int i=0;i<Ci;i++){
    float2 v=*(const float2*)&hb[(long)i*SP3];
    const float4* wc=(const float4*)&wt[i*CO];
    #pragma unroll
    for(int o4=0;o4<CO/4;o4++){
      float4 ww=wc[o4];
      acc0[4*o4+0]+=v.x*ww.x; acc0[4*o4+1]+=v.x*ww.y;
      acc0[4*o4+2]+=v.x*ww.z; acc0[4*o4+3]+=v.x*ww.w;
      acc1[4*o4+0]+=v.y*ww.x; acc1[4*o4+1]+=v.y*ww.y;
      acc1[4*o4+2]+=v.y*ww.z; acc1[4*o4+3]+=v.y*ww.w;
    }
  }
  #pragma unroll
  for(int o=0;o<CO;o++){
    *(float2*)&hb[(long)o*SP3]=make_float2(acc0[o],acc1[o]);
  }
}

// ------------- prep: transpose w1 (unchanged)
__global__ void k_prep_w1t(const float* __restrict__ w1, float* __restrict__ w1t){
  int idx=blockIdx.x*256+threadIdx.x;
  if(idx<4096){ int jj=idx>>5, i=idx&31; w1t[idx]=w1[i*128+jj]; }
}

// ------------- head, scalar-operand weights (unchanged)
__global__ __launch_bounds__(256,3) void k_head_s(const float* __restrict__ h,
                       const float* __restrict__ w1t, const float* __restrict__ b1,
                       const float* __restrict__ w2, const float* __restrict__ b2,
                       float* __restrict__ out){
  long p=(long)blockIdx.x*512+threadIdx.x;
  int b=(int)(p/SP3); int sp=(int)(p-(long)b*SP3);
  const float* hb=h+(long)b*32*SP3+sp;
  float hv0[32],hv1[32];
  #pragma unroll
  for(int i=0;i<32;i++){hv0[i]=hb[(long)i*SP3]; hv1[i]=hb[(long)i*SP3+256];}
  float a00=b2[0],a01=b2[1],a02=b2[2];
  float a10=a00,a11=a01,a12=a02;
  for(int jj=0;jj<128;jj++){
    const float* wc=w1t+jj*32;
    float u0=b1[jj], u1=u0;
    #pragma unroll
    for(int q=0;q<32;q++){
      float ww=wc[q];
      u0+=hv0[q]*ww;
      u1+=hv1[q]*ww;
    }
    u0=gelu_f(u0); u1=gelu_f(u1);
    float w20=w2[jj*3], w21=w2[jj*3+1], w22=w2[jj*3+2];
    a00+=u0*w20; a01+=u0*w21; a02+=u0*w22;
    a10+=u1*w20; a11+=u1*w21; a12+=u1*w22;
  }
  float* op=out+p*3;
  op[0]=a00; op[1]=a01; op[2]=a02;
  op=out+(p+256)*3;
  op[0]=a10; op[1]=a11; op[2]=a12;
}

// ------------- head fallback (LDS weights) for the low-workspace path
__global__ __launch_bounds__(256,4) void k_head2(const float* __restrict__ h,
                       const float* __restrict__ w1, const float* __restrict__ b1,
                       const float* __restrict__ w2, const float* __restrict__ b2,
                       float* __restrict__ out){
  __shared__ __align__(16) float w1t[128*32];
  __shared__ float b1l[128];
  __shared__ __align__(16) float4 w2l[128];
  __shared__ float b2l[3];
  int tid=threadIdx.x;
  for(int idx=tid;idx<4096;idx+=256){int jj=idx>>5,i=idx&31; w1t[idx]=w1[i*128+jj];}
  if(tid<128){b1l[tid]=b1[tid]; w2l[tid]=make_float4(w2[tid*3],w2[tid*3+1],w2[tid*3+2],0.f);}
  if(tid<3) b2l[tid]=b2[tid];
  __syncthreads();
  long p=(long)blockIdx.x*512+tid;
  int b=(int)(p/SP3); int sp=(int)(p-(long)b*SP3);
  const float* hb=h+(long)b*32*SP3+sp;
  float hv0[32],hv1[32];
  #pragma unroll
  for(int i=0;i<32;i++){hv0[i]=hb[(long)i*SP3]; hv1[i]=hb[(long)i*SP3+256];}
  float a00=b2l[0],a01=b2l[1],a02=b2l[2];
  float a10=a00,a11=a01,a12=a02;
  for(int jj=0;jj<128;jj++){
    const float4* wc=(const float4*)&w1t[jj*32];
    float u0=b1l[jj], u1=u0;
    #pragma unroll
    for(int q=0;q<8;q++){
      float4 ww=wc[q];
      u0+=hv0[4*q]*ww.x+hv0[4*q+1]*ww.y+hv0[4*q+2]*ww.z+hv0[4*q+3]*ww.w;
      u1+=hv1[4*q]*ww.x+hv1[4*q+1]*ww.y+hv1[4*q+2]*ww.z+hv1[4*q+3]*ww.w;
    }
    u0=gelu_f(u0); u1=gelu_f(u1);
    float4 w2v=w2l[jj];
    a00+=u0*w2v.x; a01+=u0*w2v.y; a02+=u0*w2v.z;
    a10+=u1*w2v.x; a11+=u1*w2v.y; a12+=u1*w2v.z;
  }
  float* op=out+p*3;
  op[0]=a00; op[1]=a01; op[2]=a02;
  op=out+(p+256)*3;
  op[0]=a10; op[1]=a11; op[2]=a12;
}

extern "C" void kernel_launch(void* const* d_in, const int* in_sizes, int n_in,
                              void* d_out, int out_size, void* d_ws, size_t ws_size,
                              hipStream_t stream){
  (void)in_sizes; (void)n_in; (void)out_size;
  const float* x    =(const float*)d_in[0];
  const float* fc0w =(const float*)d_in[1];
  const float* fc0b =(const float*)d_in[2];
  const float* sw[4]={(const float*)d_in[3],(const float*)d_in[6],(const float*)d_in[9],(const float*)d_in[12]};
  const float* cw[4]={(const float*)d_in[4],(const float*)d_in[7],(const float*)d_in[10],(const float*)d_in[13]};
  const float* cb[4]={(const float*)d_in[5],(const float*)d_in[8],(const float*)d_in[11],(const float*)d_in[14]};
  const float* fc1w =(const float*)d_in[15];
  const float* fc1b =(const float*)d_in[16];
  const float* fc2w =(const float*)d_in[17];
  const float* fc2b =(const float*)d_in[18];
  float* out=(float*)d_out;
  float* ws=(float*)d_ws;

  const long H_FLOATS   = 41943040L;
  const long FTY_FULL   = 6291456L;
  const long FM_FULL    = 1179648L;
  const long NEED_FULL  = H_FLOATS + FTY_FULL + 2*FM_FULL;

  float* h = ws;
  bool full = (ws_size >= (size_t)NEED_FULL*4);

  const int LAY[5]={20,24,24,32,32};
  const int M1A[4]={8,8,12,12};

  k_fc0<<<5120,256,0,stream>>>(x,fc0w,fc0b,h);

  for(int L=0;L<4;L++){
    int Ci=LAY[L], Co=LAY[L+1], m1=M1A[L], m2=M1A[L];
    int nch=m1*m2;
    long FM_B=(long)32*(2*m1)*(2*m2*8)*2;

    if(full){
      float* Fty=ws+H_FLOATS;
      float* Fm =ws+H_FLOATS+FTY_FULL;
      float* Fm2=ws+H_FLOATS+FTY_FULL+FM_FULL;
      if(m1==8)  k_fwd_ty8<8> <<<4*Ci*16,512,0,stream>>>(h,Fty,Ci);
      else       k_fwd_ty8<12><<<4*Ci*16,512,0,stream>>>(h,Fty,Ci);
      if(m1==8)  k_fwd_x2<8,8>  <<<4*Ci*2,256,0,stream>>>(Fty,Fm,Ci);
      else       k_fwd_x2<12,12><<<4*Ci*2,256,0,stream>>>(Fty,Fm,Ci);
      k_mix<<<4*4*nch,Co*8,0,stream>>>(Fm,sw[L],Fm2,Ci,Co,m1,m2);
      if(Co==24) k_pconv2<24><<<2560,256,0,stream>>>(h,cw[L],cb[L],Ci);
      else       k_pconv2<32><<<2560,256,0,stream>>>(h,cw[L],cb[L],Ci);
      if(m1==8)  k_inv_ytx8<8> <<<4*Co*16,512,0,stream>>>(Fm2,h,Co,(L!=3)?1:0);
      else       k_inv_ytx8<12><<<4*Co*16,512,0,stream>>>(Fm2,h,Co,(L!=3)?1:0);
    } else {
      float* Fty=out;
      float* Fm =out+1572864;
      float* Fm2=out+1867776;
      for(int b=0;b<4;b++){
        float* hbp=h+(long)b*32*SP3;
        if(m1==8)  k_fwd_ty8<8> <<<Ci*16,512,0,stream>>>(hbp,Fty,Ci);
        else       k_fwd_ty8<12><<<Ci*16,512,0,stream>>>(hbp,Fty,Ci);
        if(m1==8)  k_fwd_x2<8,8>  <<<Ci*2,256,0,stream>>>(Fty,Fm,Ci);
        else       k_fwd_x2<12,12><<<Ci*2,256,0,stream>>>(Fty,Fm,Ci);
        k_mix<<<4*nch,Co*8,0,stream>>>(Fm,sw[L],Fm2+b*FM_B,Ci,Co,m1,m2);
      }
      if(Co==24) k_pconv2<24><<<2560,256,0,stream>>>(h,cw[L],cb[L],Ci);
      else       k_pconv2<32><<<2560,256,0,stream>>>(h,cw[L],cb[L],Ci);
      for(int b=0;b<4;b++){
        float* hbp=h+(long)b*32*SP3;
        if(m1==8)  k_inv_ytx8<8> <<<Co*16,512,0,stream>>>(Fm2+b*FM_B,hbp,Co,(L!=3)?1:0);
        else       k_inv_ytx8<12><<<Co*16,512,0,stream>>>(Fm2+b*FM_B,hbp,Co,(L!=3)?1:0);
      }
    }
  }
  if(full){
    float* w1t=ws+H_FLOATS+FTY_FULL;
    k_prep_w1t<<<16,256,0,stream>>>(fc1w,w1t);
    k_head_s<<<2560,256,0,stream>>>(h,w1t,fc1b,fc2w,fc2b,out);
  } else {
    k_head2<<<2560,256,0,stream>>>(h,fc1w,fc1b,fc2w,fc2b,out);
  }
}

// Round 21
// 1425.175 us; speedup vs baseline: 1.0145x; 1.0031x over previous
//
#include <hip/hip_runtime.h>

#define TWO_PI 6.2831853071795864769f
#define SP3 327680      // 128*128*20
#define YT 2560         // 128*20

// cos/sin(2*pi*k/20) — compile-time twiddles; (kz*t)%20 indexes fold to literals.
static constexpr float TWC20[20]={
  1.0f, 0.9510565163f, 0.8090169944f, 0.5877852523f, 0.3090169944f,
  0.0f,-0.3090169944f,-0.5877852523f,-0.8090169944f,-0.9510565163f,
 -1.0f,-0.9510565163f,-0.8090169944f,-0.5877852523f,-0.3090169944f,
  0.0f, 0.3090169944f, 0.5877852523f, 0.8090169944f, 0.9510565163f};
static constexpr float TWS20[20]={
  0.0f, 0.3090169944f, 0.5877852523f, 0.8090169944f, 0.9510565163f,
  1.0f, 0.9510565163f, 0.8090169944f, 0.5877852523f, 0.3090169944f,
  0.0f,-0.3090169944f,-0.5877852523f,-0.8090169944f,-0.9510565163f,
 -1.0f,-0.9510565163f,-0.8090169944f,-0.5877852523f,-0.3090169944f};

// Branch-free gelu via A&S 7.1.26 erf approximation (|eps|<=1.5e-7).
static __device__ __forceinline__ float gelu_f(float u){
  float x=u*0.7071067811865475f;
  float a=fabsf(x);
  float t=__builtin_amdgcn_rcpf(fmaf(0.3275911f,a,1.0f));
  float p=fmaf(fmaf(fmaf(fmaf(1.061405429f,t,-1.453152027f),t,1.421413741f),t,
               -0.284496736f),t,0.254829592f)*t;
  float e=__expf(-a*a);
  float er=copysignf(1.0f-p*e,x);
  return 0.5f*u*(1.0f+er);
}

// ---------------- fc0 (unchanged)
__global__ void k_fc0(const float* __restrict__ x, const float* __restrict__ w,
                      const float* __restrict__ bias, float* __restrict__ h){
  __shared__ float wl[100], bl[20];
  int tid=threadIdx.x;
  if(tid<100) wl[tid]=w[tid];
  if(tid<20) bl[tid]=bias[tid];
  __syncthreads();
  int p=blockIdx.x*256+tid;
  int b=p/SP3, sp=p-b*SP3;
  const float* xp=x+(long)p*5;
  float xi[5];
  #pragma unroll
  for(int i=0;i<5;i++) xi[i]=xp[i];
  float* hb=h+(long)(b*32)*SP3+sp;
  #pragma unroll
  for(int c=0;c<20;c++){
    float a=bl[c];
    #pragma unroll
    for(int i=0;i<5;i++) a+=xi[i]*wl[i*20+c];
    hb[(long)c*SP3]=a;
  }
}

// ------------- forward T+Y DFT over 8-x slabs (unchanged — known good)
template<int M2>
__global__ __launch_bounds__(512,3) void k_fwd_ty8(const float* __restrict__ h,
                                                   float* __restrict__ Fty, int Ci){
  constexpr int J=2*M2*8;
  __shared__ float2 Gc[128*33];         // [y][col=xl*8+kz], pad 33
  __shared__ float2 tw128[128];
  int tid=threadIdx.x;
  int bid=blockIdx.x;
  int xg=bid&15, bc=bid>>4; int c=bc%Ci, b=bc/Ci;
  int x0=xg*8;
  if(tid<128){ float s,cc; sincosf(TWO_PI*tid/128.0f,&s,&cc); tw128[tid]=make_float2(cc,s); }
  __syncthreads();
  const float* hb=h+(long)(b*32+c)*SP3+x0*YT;
  float2* outp=(float2*)Fty+((long)(b*32+c)*128+x0)*J;

  for(int half=0;half<2;half++){
    if(half) __syncthreads();
    // ---- T-DFT: one row per thread, radix-2 over t, literal twiddles
    {
      int y=tid&127, xl=tid>>7;
      const float* rp=hb+(half*4+xl)*YT+y*20;
      float4 r0=*(const float4*)(rp);
      float4 r1=*(const float4*)(rp+4);
      float4 r2=*(const float4*)(rp+8);
      float4 r3=*(const float4*)(rp+12);
      float4 r4=*(const float4*)(rp+16);
      float row[20]={r0.x,r0.y,r0.z,r0.w, r1.x,r1.y,r1.z,r1.w, r2.x,r2.y,r2.z,r2.w,
                     r3.x,r3.y,r3.z,r3.w, r4.x,r4.y,r4.z,r4.w};
      float av[10],bv[10];
      #pragma unroll
      for(int t=0;t<10;t++){av[t]=row[t]+row[t+10]; bv[t]=row[t]-row[t+10];}
      float re[8],im[8];
      #pragma unroll
      for(int kz=0;kz<8;kz++){re[kz]=0.f;im[kz]=0.f;}
      #pragma unroll
      for(int t=0;t<10;t++){
        #pragma unroll
        for(int kz=0;kz<8;kz++){
          float v=(kz&1)?bv[t]:av[t];
          re[kz]+=v*TWC20[(kz*t)%20];
          im[kz]-=v*TWS20[(kz*t)%20];
        }
      }
      #pragma unroll
      for(int kz=0;kz<8;kz++) Gc[y*33+xl*8+kz]=make_float2(re[kz],im[kz]);
    }
    __syncthreads();
    // ---- radix-2 precombine: Gc[y] <- G[y]+G[y+64]; Gc[y+64] <- G[y]-G[y+64]
    for(int pi=tid;pi<2048;pi+=512){
      int y=pi>>5, col=pi&31;
      float2 a=Gc[y*33+col], bb=Gc[(y+64)*33+col];
      Gc[y*33+col]      =make_float2(a.x+bb.x, a.y+bb.y);
      Gc[(y+64)*33+col] =make_float2(a.x-bb.x, a.y-bb.y);
    }
    __syncthreads();
    // ---- Y-DFT: item=(sp,col), sp in [0,M2], 64-y loop, parity-selected half
    for(int ip=tid;ip<(M2+1)*32;ip+=512){
      int col=ip&31, sp=ip>>5;
      int off=(sp&1)?64:0;
      float a1r=0.f,a1i=0.f,a2r=0.f,a2i=0.f;
      int jj=0;
      for(int y=0;y<64;y++){
        float2 w=tw128[jj];
        float2 d=Gc[(y+off)*33+col];
        float tr=d.x*w.x, ts=d.y*w.y, ur=d.y*w.x, us=d.x*w.y;
        a1r+=tr+ts; a1i+=ur-us;          // slot sp      (km=+sp)
        a2r+=tr-ts; a2i+=ur+us;          // slot 2M2-sp  (km=-sp)
        jj=(jj+sp)&127;
      }
      int xl=col>>3, kz=col&7;
      long rowoff=(long)(half*4+xl)*J;
      if(sp<M2) outp[rowoff+sp*8+kz]=make_float2(a1r,a1i);
      if(sp>=1) outp[rowoff+(2*M2-sp)*8+kz]=make_float2(a2r,a2i);
    }
  }
}

// ------------- forward X DFT, slot-split (unchanged)
template<int M1,int M2>
__global__ __launch_bounds__(256,3) void k_fwd_x2(const float* __restrict__ Fty,
                                                  float* __restrict__ Fm, int Ci){
  constexpr int J=2*M2*8;
  constexpr int NIT=(M1*J+255)/256;
  __shared__ float2 tile[32*J];
  __shared__ float2 tw128[128];
  int tid=threadIdx.x, bid=blockIdx.x;
  int sh=bid&1; int c=(bid>>1)%Ci; int b=bid/(2*Ci);
  if(tid<128){ float s,cc; sincosf(TWO_PI*tid/128.0f,&s,&cc); tw128[tid]=make_float2(cc,s); }
  float accr[NIT],acci[NIT];
  #pragma unroll
  for(int it=0;it<NIT;it++){accr[it]=0.f;acci[it]=0.f;}
  const float2* base=(const float2*)Fty+((long)(b*32+c)*128)*J;
  for(int xt=0;xt<4;xt++){
    __syncthreads();
    const float2* src=base+(long)xt*32*J;
    for(int idx=tid;idx<32*J;idx+=256) tile[idx]=src[idx];
    __syncthreads();
    #pragma unroll
    for(int it=0;it<NIT;it++){
      int idx=it*256+tid;
      if(idx<M1*J){
        int si=idx/J, j=idx-si*J;
        int km=(sh==0)? si : (si-M1);
        int jj=(km*(xt*32))&127;
        float ar=accr[it], ai=acci[it];
        for(int xl=0;xl<32;xl++){
          float2 w=tw128[jj];
          float2 d=tile[xl*J+j];
          ar+=d.x*w.x+d.y*w.y;
          ai+=d.y*w.x-d.x*w.y;
          jj=(jj+km)&127;
        }
        accr[it]=ar; acci[it]=ai;
      }
    }
  }
  float2* o=(float2*)Fm+(long)(b*32+c)*(2*M1)*J;
  #pragma unroll
  for(int it=0;it<NIT;it++){
    int idx=it*256+tid;
    if(idx<M1*J){
      int si=idx/J, j=idx-si*J;
      int s=sh*M1+si;
      o[(long)s*J+j]=make_float2(accr[it],acci[it]);
    }
  }
}

// ------------- mode mixing (unchanged)
__global__ void k_mix(const float* __restrict__ Fm, const float* __restrict__ w,
                      float* __restrict__ Fm2, int Ci, int Co, int m1, int m2){
  int MC=m1*m2*8;
  int nch=MC/8;
  int bid=blockIdx.x;
  int chunk=bid%nch; int q=(bid/nch)&3; int b=bid/(4*nch);
  int tid=threadIdx.x;
  int M1S=2*m1, M2S=2*m2;
  int J=M2S*8;
  __shared__ float fin[32*16];
  for(int idx=tid;idx<Ci*16;idx+=blockDim.x){
    int i=idx>>4; int r=idx&15; int mll=r>>1; int ri=r&1;
    int mg=chunk*8+mll;
    int mx=mg/(m2*8); int my=(mg>>3)%m2; int kz=mg&7;
    int sx=(q&1)?(m1+mx):mx; int sy=(q&2)?(m2+my):my;
    fin[idx]=Fm[((long)((b*32+i)*M1S+sx)*J+sy*8+kz)*2+ri];
  }
  __syncthreads();
  int ml=tid&7, o=tid>>3;
  int mg=chunk*8+ml;
  int mx=mg/(m2*8); int my=(mg>>3)%m2; int kz=mg&7;
  int sx=(q&1)?(m1+mx):mx; int sy=(q&2)?(m2+my):my;
  int moff=(mx*m2+my)*8+kz;
  const float* wr=w+(long)(q*2)*Ci*Co*MC+o*MC+moff;
  const float* wi=wr+(long)Ci*Co*MC;
  long wstep=(long)Co*MC;
  float re=0.f, im=0.f;
  for(int i=0;i<Ci;i++){
    float ar=fin[i*16+ml*2], ai=fin[i*16+ml*2+1];
    float wrv=wr[i*wstep], wiv=wi[i*wstep];
    re+=ar*wrv-ai*wiv;
    im+=ar*wiv+ai*wrv;
  }
  long oidx=((long)((b*32+o)*M1S+sx)*J+sy*8+kz)*2;
  Fm2[oidx]=re; Fm2[oidx+1]=im;
}

// ------------- FUSED inverse X + Y + T, single-pass radix-2-over-y inverse-Y.
// Inverse-X conj-paired over (s, S1-s): one tw read + one jj chain serves both.
// VGPR diet: row y+64's inverse-T recomputed after flush 1 (no o2[]).
template<int M>
__global__ __launch_bounds__(512,3) void k_inv_ytx8(const float* __restrict__ Fm2,
                                                    float* h, int Co, int do_gelu){
  constexpr int S1=2*M, S2=2*M;
  constexpr int J=S2*8;
  constexpr int FMS=S1*J*2;            // floats for Fm2s
  constexpr int G1F=S2*66*2;           // floats for g1s
  constexpr int UNF=(FMS+G1F>10752)?(FMS+G1F):10752;
  __shared__ __align__(16) float buf[UNF];     // Fm2s|g1s, later So
  __shared__ float2 tw128[128];
  int tid=threadIdx.x;
  int bid=blockIdx.x;
  int xg=bid&15, bo=bid>>4; int oc=bo%Co, b=bo/Co;
  int x0=xg*8;
  if(tid<128){ float s,cc; sincosf(TWO_PI*tid/128.0f,&s,&cc); tw128[tid]=make_float2(cc,s); }
  // ---- stage Fm2 tile (coalesced)
  float2* Fm2s=(float2*)buf;
  float2* g1s=(float2*)(buf+FMS);
  const float2* src=(const float2*)Fm2+(long)(b*32+oc)*S1*J;
  for(int idx=tid;idx<S1*J;idx+=512) Fm2s[idx]=src[idx];
  __syncthreads();
  // ---- inverse X: conj-paired (s, S1-s); float2 reads, uniform tw broadcasts.
  for(int idx=tid;idx<8*J;idx+=512){
    int xl=idx/J, j=idx-xl*J;
    int xgl=x0+xl;
    // s=0: w=1
    float2 d0=Fm2s[j];
    float re=d0.x, im=d0.y;
    // pairs s=1..M-1 (km=+s) with S1-s (km=-s): conjugate twiddles
    int jj=xgl&127;
    for(int s=1;s<M;s++){
      float2 w=tw128[jj];
      float2 F1=Fm2s[s*J+j], F2=Fm2s[(S1-s)*J+j];
      re+=(F1.x+F2.x)*w.x-(F1.y-F2.y)*w.y;
      im+=(F1.x-F2.x)*w.y+(F1.y+F2.y)*w.x;
      jj=(jj+xgl)&127;
    }
    // s=M: km=-M
    {
      int jm=((128-M)*xgl)&127;
      float2 w=tw128[jm];
      float2 d=Fm2s[M*J+j];
      re+=d.x*w.x-d.y*w.y;
      im+=d.x*w.y+d.y*w.x;
    }
    g1s[(j>>3)*66 + xl*8 + (j&7)]=make_float2(re,im);
  }
  __syncthreads();                      // Fm2s dead (g1s live)
  float* So=buf;                        // overlays Fm2s+g1s — write only after
                                        // the post-accumulation barrier below
  const float invN=1.0f/(128.0f*128.0f*20.0f);
  float* hb=h+(long)(b*32+oc)*SP3+x0*YT;
  const float4* g4c=(const float4*)g1s;
  int y=tid&63, xl=tid>>6;              // xl wave-uniform (0..7)
  float Ser[8],Sei[8],Sor[8],Soi[8];
  // s=0 (km=0, w=1, even parity)
  {
    int base=(xl*8)>>1;
    #pragma unroll
    for(int q=0;q<4;q++){
      float4 d=g4c[base+q];
      Ser[2*q]=d.x;   Sei[2*q]=d.y;
      Ser[2*q+1]=d.z; Sei[2*q+1]=d.w;
      Sor[2*q]=0.f;   Soi[2*q]=0.f;
      Sor[2*q+1]=0.f; Soi[2*q+1]=0.f;
    }
  }
  // s=M (km=-M, M even -> even parity)
  {
    int jm=((128-M)*y)&127;
    float ang=(float)jm*(TWO_PI/128.0f);
    float wx=__cosf(ang), wy=__sinf(ang);
    int base=(M*66+xl*8)>>1;
    #pragma unroll
    for(int q=0;q<4;q++){
      float4 d=g4c[base+q];
      Ser[2*q]  +=d.x*wx-d.y*wy;  Sei[2*q]  +=d.x*wy+d.y*wx;
      Ser[2*q+1]+=d.z*wx-d.w*wy;  Sei[2*q+1]+=d.z*wy+d.w*wx;
    }
  }
  // conjugate pairs (s, S2-s), s=1..M-1: one sincos, parity-routed by s&1
  for(int s=1;s<M;s++){
    int jm=(s*y)&127;
    float ang=(float)jm*(TWO_PI/128.0f);
    float c=__cosf(ang), sn=__sinf(ang);
    int b1=(s*66+xl*8)>>1, b2=((S2-s)*66+xl*8)>>1;
    if(s&1){
      #pragma unroll
      for(int q=0;q<4;q++){
        float4 d1=g4c[b1+q], d2=g4c[b2+q];
        float Ax=d1.x+d2.x, By=d1.y-d2.y, Bx=d1.x-d2.x, Ay=d1.y+d2.y;
        Sor[2*q]  +=Ax*c-By*sn;  Soi[2*q]  +=Bx*sn+Ay*c;
        float Az=d1.z+d2.z, Bw=d1.w-d2.w, Bz=d1.z-d2.z, Aw=d1.w+d2.w;
        Sor[2*q+1]+=Az*c-Bw*sn;  Soi[2*q+1]+=Bz*sn+Aw*c;
      }
    }else{
      #pragma unroll
      for(int q=0;q<4;q++){
        float4 d1=g4c[b1+q], d2=g4c[b2+q];
        float Ax=d1.x+d2.x, By=d1.y-d2.y, Bx=d1.x-d2.x, Ay=d1.y+d2.y;
        Ser[2*q]  +=Ax*c-By*sn;  Sei[2*q]  +=Bx*sn+Ay*c;
        float Az=d1.z+d2.z, Bw=d1.w-d2.w, Bz=d1.z-d2.z, Aw=d1.w+d2.w;
        Ser[2*q+1]+=Az*c-Bw*sn;  Sei[2*q+1]+=Bz*sn+Aw*c;
      }
    }
  }
  __syncthreads();                      // all g1s reads done; So may now overlay
  int srow=xl*64+y;
  // ---- inverse-T for row y (E1 = Ae+Be, O1 = Ao+Bo); write So.
  #pragma unroll
  for(int t=0;t<10;t++){
    float Ae=Ser[0], Be=Sor[0], Ao=0.f, Bo=0.f;
    #pragma unroll
    for(int kz=1;kz<8;kz++){
      float C2=2.0f*TWC20[(kz*t)%20], Sv=2.0f*TWS20[(kz*t)%20];
      if(kz&1){ Ao+=C2*Ser[kz]-Sv*Sei[kz]; Bo+=C2*Sor[kz]-Sv*Soi[kz]; }
      else    { Ae+=C2*Ser[kz]-Sv*Sei[kz]; Be+=C2*Sor[kz]-Sv*Soi[kz]; }
    }
    float E1=Ae+Be, O1=Ao+Bo;
    So[srow*21+t]   =(E1+O1)*invN;
    So[srow*21+t+10]=(E1-O1)*invN;
  }
  __syncthreads();
  // ---- flush half 1: y<64 parts of all 8 rows (8 x 1280 contiguous floats)
  for(int f=tid;f<10240;f+=512){
    int xf=f/1280, rem=f-xf*1280;
    int rr=rem/20, t=rem-rr*20;
    float* dst=&hb[xf*YT+rem];
    float u=*dst+So[(xf*64+rr)*21+t];
    if(do_gelu) u=gelu_f(u);
    *dst=u;
  }
  __syncthreads();
  // ---- inverse-T for row y+64 (E2 = Ae-Be, O2 = Ao-Bo), recomputed; write So.
  #pragma unroll
  for(int t=0;t<10;t++){
    float Ae=Ser[0], Be=Sor[0], Ao=0.f, Bo=0.f;
    #pragma unroll
    for(int kz=1;kz<8;kz++){
      float C2=2.0f*TWC20[(kz*t)%20], Sv=2.0f*TWS20[(kz*t)%20];
      if(kz&1){ Ao+=C2*Ser[kz]-Sv*Sei[kz]; Bo+=C2*Sor[kz]-Sv*Soi[kz]; }
      else    { Ae+=C2*Ser[kz]-Sv*Sei[kz]; Be+=C2*Sor[kz]-Sv*Soi[kz]; }
    }
    float E2=Ae-Be, O2v=Ao-Bo;
    So[srow*21+t]   =(E2+O2v)*invN;
    So[srow*21+t+10]=(E2-O2v)*invN;
  }
  __syncthreads();
  // ---- flush half 2: y>=64 parts (contiguous, offset 1280 within each row)
  for(int f=tid;f<10240;f+=512){
    int xf=f/1280, rem=f-xf*1280;
    int rr=rem/20, t=rem-rr*20;
    float* dst=&hb[xf*YT+1280+rem];
    float u=*dst+So[(xf*64+rr)*21+t];
    if(do_gelu) u=gelu_f(u);
    *dst=u;
  }
}

// ------------- pointwise conv IN-PLACE (unchanged)
template<int CO>
__global__ __launch_bounds__(256,4) void k_pconv2(float* h, const float* __restrict__ w,
                                                  const float* __restrict__ bias, int Ci){
  __shared__ __align__(16) float wt[32*CO];   // [i][o]
  __shared__ float bl[CO];
  int tid=threadIdx.x;
  for(int idx=tid;idx<Ci*CO;idx+=256){int i=idx/CO,o=idx-i*CO; wt[idx]=w[o*Ci+i];}
  if(tid<CO) bl[tid]=bias[tid];
  __syncthreads();
  long p=(long)blockIdx.x*512+tid*2;
  int b=(int)(p/SP3); int sp=(int)(p-(long)b*SP3);
  float* hb=h+(long)b*32*SP3+sp;
  float acc0[CO],acc1[CO];
  #pragma unroll
  for(int o=0;o<CO;o++){acc0[o]=bl[o];acc1[o]=bl[o];}
  for(int i=0;i<Ci;i++){
    float2 v=*(const float2*)&hb[(long)i*SP3];
    const float4* wc=(const float4*)&wt[i*CO];
    #pragma unroll
    for(int o4=0;o4<CO/4;o4++){
      float4 ww=wc[o4];
      acc0[4*o4+0]+=v.x*ww.x; acc0[4*o4+1]+=v.x*ww.y;
      acc0[4*o4+2]+=v.x*ww.z; acc0[4*o4+3]+=v.x*ww.w;
      acc1[4*o4+0]+=v.y*ww.x; acc1[4*o4+1]+=v.y*ww.y;
      acc1[4*o4+2]+=v.y*ww.z; acc1[4*o4+3]+=v.y*ww.w;
    }
  }
  #pragma unroll
  for(int o=0;o<CO;o++){
    *(float2*)&hb[(long)o*SP3]=make_float2(acc0[o],acc1[o]);
  }
}

// ------------- prep: transpose w1 (unchanged)
__global__ void k_prep_w1t(const float* __restrict__ w1, float* __restrict__ w1t){
  int idx=blockIdx.x*256+threadIdx.x;
  if(idx<4096){ int jj=idx>>5, i=idx&31; w1t[idx]=w1[i*128+jj]; }
}

// ------------- head, scalar-operand weights (unchanged)
__global__ __launch_bounds__(256,3) void k_head_s(const float* __restrict__ h,
                       const float* __restrict__ w1t, const float* __restrict__ b1,
                       const float* __restrict__ w2, const float* __restrict__ b2,
                       float* __restrict__ out){
  long p=(long)blockIdx.x*512+threadIdx.x;
  int b=(int)(p/SP3); int sp=(int)(p-(long)b*SP3);
  const float* hb=h+(long)b*32*SP3+sp;
  float hv0[32],hv1[32];
  #pragma unroll
  for(int i=0;i<32;i++){hv0[i]=hb[(long)i*SP3]; hv1[i]=hb[(long)i*SP3+256];}
  float a00=b2[0],a01=b2[1],a02=b2[2];
  float a10=a00,a11=a01,a12=a02;
  for(int jj=0;jj<128;jj++){
    const float* wc=w1t+jj*32;
    float u0=b1[jj], u1=u0;
    #pragma unroll
    for(int q=0;q<32;q++){
      float ww=wc[q];
      u0+=hv0[q]*ww;
      u1+=hv1[q]*ww;
    }
    u0=gelu_f(u0); u1=gelu_f(u1);
    float w20=w2[jj*3], w21=w2[jj*3+1], w22=w2[jj*3+2];
    a00+=u0*w20; a01+=u0*w21; a02+=u0*w22;
    a10+=u1*w20; a11+=u1*w21; a12+=u1*w22;
  }
  float* op=out+p*3;
  op[0]=a00; op[1]=a01; op[2]=a02;
  op=out+(p+256)*3;
  op[0]=a10; op[1]=a11; op[2]=a12;
}

// ------------- head fallback (LDS weights) for the low-workspace path
__global__ __launch_bounds__(256,4) void k_head2(const float* __restrict__ h,
                       const float* __restrict__ w1, const float* __restrict__ b1,
                       const float* __restrict__ w2, const float* __restrict__ b2,
                       float* __restrict__ out){
  __shared__ __align__(16) float w1t[128*32];
  __shared__ float b1l[128];
  __shared__ __align__(16) float4 w2l[128];
  __shared__ float b2l[3];
  int tid=threadIdx.x;
  for(int idx=tid;idx<4096;idx+=256){int jj=idx>>5,i=idx&31; w1t[idx]=w1[i*128+jj];}
  if(tid<128){b1l[tid]=b1[tid]; w2l[tid]=make_float4(w2[tid*3],w2[tid*3+1],w2[tid*3+2],0.f);}
  if(tid<3) b2l[tid]=b2[tid];
  __syncthreads();
  long p=(long)blockIdx.x*512+tid;
  int b=(int)(p/SP3); int sp=(int)(p-(long)b*SP3);
  const float* hb=h+(long)b*32*SP3+sp;
  float hv0[32],hv1[32];
  #pragma unroll
  for(int i=0;i<32;i++){hv0[i]=hb[(long)i*SP3]; hv1[i]=hb[(long)i*SP3+256];}
  float a00=b2l[0],a01=b2l[1],a02=b2l[2];
  float a10=a00,a11=a01,a12=a02;
  for(int jj=0;jj<128;jj++){
    const float4* wc=(const float4*)&w1t[jj*32];
    float u0=b1l[jj], u1=u0;
    #pragma unroll
    for(int q=0;q<8;q++){
      float4 ww=wc[q];
      u0+=hv0[4*q]*ww.x+hv0[4*q+1]*ww.y+hv0[4*q+2]*ww.z+hv0[4*q+3]*ww.w;
      u1+=hv1[4*q]*ww.x+hv1[4*q+1]*ww.y+hv1[4*q+2]*ww.z+hv1[4*q+3]*ww.w;
    }
    u0=gelu_f(u0); u1=gelu_f(u1);
    float4 w2v=w2l[jj];
    a00+=u0*w2v.x; a01+=u0*w2v.y; a02+=u0*w2v.z;
    a10+=u1*w2v.x; a11+=u1*w2v.y; a12+=u1*w2v.z;
  }
  float* op=out+p*3;
  op[0]=a00; op[1]=a01; op[2]=a02;
  op=out+(p+256)*3;
  op[0]=a10; op[1]=a11; op[2]=a12;
}

extern "C" void kernel_launch(void* const* d_in, const int* in_sizes, int n_in,
                              void* d_out, int out_size, void* d_ws, size_t ws_size,
                              hipStream_t stream){
  (void)in_sizes; (void)n_in; (void)out_size;
  const float* x    =(const float*)d_in[0];
  const float* fc0w =(const float*)d_in[1];
  const float* fc0b =(const float*)d_in[2];
  const float* sw[4]={(const float*)d_in[3],(const float*)d_in[6],(const float*)d_in[9],(const float*)d_in[12]};
  const float* cw[4]={(const float*)d_in[4],(const float*)d_in[7],(const float*)d_in[10],(const float*)d_in[13]};
  const float* cb[4]={(const float*)d_in[5],(const float*)d_in[8],(const float*)d_in[11],(const float*)d_in[14]};
  const float* fc1w =(const float*)d_in[15];
  const float* fc1b =(const float*)d_in[16];
  const float* fc2w =(const float*)d_in[17];
  const float* fc2b =(const float*)d_in[18];
  float* out=(float*)d_out;
  float* ws=(float*)d_ws;

  const long H_FLOATS   = 41943040L;
  const long FTY_FULL   = 6291456L;
  const long FM_FULL    = 1179648L;
  const long NEED_FULL  = H_FLOATS + FTY_FULL + 2*FM_FULL;

  float* h = ws;
  bool full = (ws_size >= (size_t)NEED_FULL*4);

  const int LAY[5]={20,24,24,32,32};
  const int M1A[4]={8,8,12,12};

  k_fc0<<<5120,256,0,stream>>>(x,fc0w,fc0b,h);

  for(int L=0;L<4;L++){
    int Ci=LAY[L], Co=LAY[L+1], m1=M1A[L], m2=M1A[L];
    int nch=m1*m2;
    long FM_B=(long)32*(2*m1)*(2*m2*8)*2;

    if(full){
      float* Fty=ws+H_FLOATS;
      float* Fm =ws+H_FLOATS+FTY_FULL;
      float* Fm2=ws+H_FLOATS+FTY_FULL+FM_FULL;
      if(m1==8)  k_fwd_ty8<8> <<<4*Ci*16,512,0,stream>>>(h,Fty,Ci);
      else       k_fwd_ty8<12><<<4*Ci*16,512,0,stream>>>(h,Fty,Ci);
      if(m1==8)  k_fwd_x2<8,8>  <<<4*Ci*2,256,0,stream>>>(Fty,Fm,Ci);
      else       k_fwd_x2<12,12><<<4*Ci*2,256,0,stream>>>(Fty,Fm,Ci);
      k_mix<<<4*4*nch,Co*8,0,stream>>>(Fm,sw[L],Fm2,Ci,Co,m1,m2);
      if(Co==24) k_pconv2<24><<<2560,256,0,stream>>>(h,cw[L],cb[L],Ci);
      else       k_pconv2<32><<<2560,256,0,stream>>>(h,cw[L],cb[L],Ci);
      if(m1==8)  k_inv_ytx8<8> <<<4*Co*16,512,0,stream>>>(Fm2,h,Co,(L!=3)?1:0);
      else       k_inv_ytx8<12><<<4*Co*16,512,0,stream>>>(Fm2,h,Co,(L!=3)?1:0);
    } else {
      float* Fty=out;
      float* Fm =out+1572864;
      float* Fm2=out+1867776;
      for(int b=0;b<4;b++){
        float* hbp=h+(long)b*32*SP3;
        if(m1==8)  k_fwd_ty8<8> <<<Ci*16,512,0,stream>>>(hbp,Fty,Ci);
        else       k_fwd_ty8<12><<<Ci*16,512,0,stream>>>(hbp,Fty,Ci);
        if(m1==8)  k_fwd_x2<8,8>  <<<Ci*2,256,0,stream>>>(Fty,Fm,Ci);
        else       k_fwd_x2<12,12><<<Ci*2,256,0,stream>>>(Fty,Fm,Ci);
        k_mix<<<4*nch,Co*8,0,stream>>>(Fm,sw[L],Fm2+b*FM_B,Ci,Co,m1,m2);
      }
      if(Co==24) k_pconv2<24><<<2560,256,0,stream>>>(h,cw[L],cb[L],Ci);
      else       k_pconv2<32><<<2560,256,0,stream>>>(h,cw[L],cb[L],Ci);
      for(int b=0;b<4;b++){
        float* hbp=h+(long)b*32*SP3;
        if(m1==8)  k_inv_ytx8<8> <<<Co*16,512,0,stream>>>(Fm2+b*FM_B,hbp,Co,(L!=3)?1:0);
        else       k_inv_ytx8<12><<<Co*16,512,0,stream>>>(Fm2+b*FM_B,hbp,Co,(L!=3)?1:0);
      }
    }
  }
  if(full){
    float* w1t=ws+H_FLOATS+FTY_FULL;
    k_prep_w1t<<<16,256,0,stream>>>(fc1w,w1t);
    k_head_s<<<2560,256,0,stream>>>(h,w1t,fc1b,fc2w,fc2b,out);
  } else {
    k_head2<<<2560,256,0,stream>>>(h,fc1w,fc1b,fc2w,fc2b,out);
  }
}